// Round 10
// baseline (483.921 us; speedup 1.0000x reference)
//
#include <hip/hip_runtime.h>
#include <hip/hip_bf16.h>
#include <math.h>

#define NB 4
#define NS 2048
#define ND 768
#define NH 8
#define NDH 96
#define NHID 3072
#define NROWS (NB*NS)

typedef __attribute__((ext_vector_type(8))) short bf16x8;
typedef __attribute__((ext_vector_type(4))) float f32x4;

// async global->LDS, 16B per lane. LDS dest must be wave-uniform base (HW adds lane*16).
#define GLOAD16(gp, lp)                                                          \
    __builtin_amdgcn_global_load_lds(                                            \
        (__attribute__((address_space(1))) void*)(unsigned long long)(gp),       \
        (__attribute__((address_space(3))) void*)(unsigned long long)(lp), 16, 0, 0)

// ---------------- block-wide sum over 256 threads ----------------
static __device__ __forceinline__ float block_sum256(float v) {
    __shared__ float red[4];
    #pragma unroll
    for (int o = 32; o > 0; o >>= 1) v += __shfl_down(v, o);
    int w = threadIdx.x >> 6;
    __syncthreads();
    if ((threadIdx.x & 63) == 0) red[w] = v;
    __syncthreads();
    return red[0] + red[1] + red[2] + red[3];
}

// ---------------- LayerNorm: f32 in -> bf16 out ----------------
__global__ __launch_bounds__(256) void ln_bf16_kernel(const float* __restrict__ in,
                                                      const float* __restrict__ g,
                                                      const float* __restrict__ bta,
                                                      __hip_bfloat16* __restrict__ out) {
    int row = blockIdx.x;
    const float* x = in + (size_t)row * ND;
    int t = threadIdx.x;
    float v0 = x[t], v1 = x[t + 256], v2 = x[t + 512];
    float mu = block_sum256(v0 + v1 + v2) * (1.0f / ND);
    float d0 = v0 - mu, d1 = v1 - mu, d2 = v2 - mu;
    float var = block_sum256(d0*d0 + d1*d1 + d2*d2) * (1.0f / ND);
    float rs = rsqrtf(var + 1e-6f);
    __hip_bfloat16* o = out + (size_t)row * ND;
    o[t]       = __float2bfloat16(d0 * rs * g[t]       + bta[t]);
    o[t + 256] = __float2bfloat16(d1 * rs * g[t + 256] + bta[t + 256]);
    o[t + 512] = __float2bfloat16(d2 * rs * g[t + 512] + bta[t + 512]);
}

// ---------------- weight transpose+convert: w[K][N] f32 -> wT[N][K] bf16 ----------------
__global__ __launch_bounds__(256) void wtrans_kernel(const float* __restrict__ w,
                                                     __hip_bfloat16* __restrict__ wT,
                                                     int K, int N) {
    __shared__ float tile[32][33];
    int nb = N >> 5;
    int k0 = (blockIdx.x / nb) << 5, n0 = (blockIdx.x % nb) << 5;
    int t = threadIdx.x;
    int rr = t >> 5, cc = t & 31;
    #pragma unroll
    for (int j = 0; j < 4; ++j)
        tile[rr + j*8][cc] = w[(size_t)(k0 + rr + j*8) * N + n0 + cc];
    __syncthreads();
    #pragma unroll
    for (int j = 0; j < 4; ++j)
        wT[(size_t)(n0 + rr + j*8) * K + k0 + cc] = __float2bfloat16(tile[cc][rr + j*8]);
}

// ---------------- bf16 MFMA GEMM: C[M][N] = A[M][K] * BT[N][K]^T ----------------
// 128x128 tile, BK=64, 256 thr (4 waves 2x2), global_load_lds w/ XOR-swizzled source.
// XCD-chunked blockIdx remap (T1, bijective: all grids %8==0).
// EPI: 0 = +bias, scatter bf16 q/k [bh][s][dh], v TRANSPOSED [bh][dh][s];
//      1 = +bias+res -> f32; 2 = +bias+GELU -> bf16
template<int EPI>
__global__ __launch_bounds__(256) void gemm_mfma(
        const __hip_bfloat16* __restrict__ A, const __hip_bfloat16* __restrict__ BT,
        const float* __restrict__ bias, int M, int N, int K,
        float* __restrict__ Cf, const float* __restrict__ res,
        __hip_bfloat16* __restrict__ Cb,
        __hip_bfloat16* __restrict__ qo, __hip_bfloat16* __restrict__ ko,
        __hip_bfloat16* __restrict__ vo) {
    __shared__ __attribute__((aligned(16))) __hip_bfloat16 As[128][64];
    __shared__ __attribute__((aligned(16))) __hip_bfloat16 Bs[128][64];
    // XCD-aware remap: each XCD gets a contiguous chunk of x-major block order
    int gxd = gridDim.x;
    int lin = blockIdx.y * gxd + blockIdx.x;
    int cpx = (gxd * gridDim.y) >> 3;
    int lin2 = (lin & 7) * cpx + (lin >> 3);
    int bx = lin2 % gxd, by = lin2 / gxd;
    int t = threadIdx.x, w = t >> 6, l = t & 63;
    int lr = l & 15, lg = l >> 4;
    int wr = w >> 1, wc = w & 1;

    int off  = w * 1024 + l * 16;
    int srow = off >> 7;
    int scol = off & 127;
    int scolS = scol ^ ((srow & 7) << 4);
    const char* ap = (const char*)(A  + (size_t)(by * 128 + srow) * K) + scolS;
    const char* bp = (const char*)(BT + (size_t)(bx * 128 + srow) * K) + scolS;
    size_t rstep = (size_t)32 * K * 2;
    char* asl = ((char*)As) + w * 1024;
    char* bsl = ((char*)Bs) + w * 1024;

    f32x4 acc[4][4];
    #pragma unroll
    for (int i = 0; i < 4; ++i)
        #pragma unroll
        for (int j = 0; j < 4; ++j) acc[i][j] = (f32x4){0.f, 0.f, 0.f, 0.f};

    int mask = (lr & 7) << 4;
    const char* asb = (const char*)As;
    const char* bsb = (const char*)Bs;

    for (int k0 = 0; k0 < K; k0 += 64) {
        __syncthreads();
        #pragma unroll
        for (int i = 0; i < 4; ++i) {
            GLOAD16(ap + i * rstep, asl + i * 4096);
            GLOAD16(bp + i * rstep, bsl + i * 4096);
        }
        ap += 128; bp += 128;
        __syncthreads();
        #pragma unroll
        for (int ks = 0; ks < 2; ++ks) {
            bf16x8 a[4], b[4];
            #pragma unroll
            for (int x = 0; x < 4; ++x) {
                int ra = (wr << 6) + x*16 + lr;
                int rb = (wc << 6) + x*16 + lr;
                int cb = ((ks * 64 + lg * 16) ^ mask);
                a[x] = *(const bf16x8*)(asb + ra * 128 + cb);
                b[x] = *(const bf16x8*)(bsb + rb * 128 + cb);
            }
            #pragma unroll
            for (int mt = 0; mt < 4; ++mt)
                #pragma unroll
                for (int nt = 0; nt < 4; ++nt)
                    acc[mt][nt] = __builtin_amdgcn_mfma_f32_16x16x32_bf16(a[mt], b[nt], acc[mt][nt], 0, 0, 0);
        }
    }

    int rbase = by * 128 + (wr << 6) + lg * 4;
    int cbase = bx * 128 + (wc << 6) + lr;
    #pragma unroll
    for (int nt = 0; nt < 4; ++nt) {
        int gc = cbase + nt * 16;
        float bv = bias[gc];
        #pragma unroll
        for (int mt = 0; mt < 4; ++mt) {
            #pragma unroll
            for (int rr = 0; rr < 4; ++rr) {
                int gr = rbase + mt * 16 + rr;
                float val = acc[mt][nt][rr] + bv;
                if (EPI == 0) {
                    int which = gc / ND;
                    int ccc = gc - which * ND;
                    int hh = ccc / NDH, dd = ccc - hh * NDH;
                    int b_ = gr >> 11, s_ = gr & (NS - 1);
                    __hip_bfloat16 bval = __float2bfloat16(val);
                    if (which == 0)
                        qo[(size_t)((b_ * NH + hh) * NS + s_) * NDH + dd] = bval;
                    else if (which == 1)
                        ko[(size_t)((b_ * NH + hh) * NS + s_) * NDH + dd] = bval;
                    else   // V transposed: [bh][dh][s]
                        vo[(size_t)((b_ * NH + hh) * NDH + dd) * NS + s_] = bval;
                } else if (EPI == 1) {
                    Cf[(size_t)gr * N + gc] = res[(size_t)gr * N + gc] + val;
                } else {
                    Cb[(size_t)gr * N + gc] =
                        __float2bfloat16(0.5f * val * (1.0f + erff(val * 0.70710678118f)));
                }
            }
        }
    }
}

// ---------------- 3D RoPE: rotate q,k bf16 in place ----------------
__global__ __launch_bounds__(256) void rope_bf16_kernel(const float* __restrict__ coords,
                                                        __hip_bfloat16* __restrict__ q,
                                                        __hip_bfloat16* __restrict__ k) {
    __shared__ float tile[64][97];
    __shared__ float cst[64][49];
    __shared__ float snt[64][49];
    int nblk = NS / 64;
    int bh = blockIdx.x / nblk;
    int s0 = (blockIdx.x % nblk) * 64;
    int b_ = bh / NH;
    int t = threadIdx.x;
    for (int i = t; i < 64 * 48; i += 256) {
        int sl = i / 48, f = i - sl * 48;
        int axis = f >> 4, j = f & 15;
        float c = coords[(size_t)(b_ * NS + s0 + sl) * 3 + axis];
        float ang = c * powf(10000.0f, -(float)j * (1.0f / 16.0f));
        float sv, cv;
        sincosf(ang, &sv, &cv);
        cst[sl][f] = cv; snt[sl][f] = sv;
    }
    size_t base = (size_t)(bh * NS + s0) * NDH;
    __hip_bfloat16* ptrs[2] = {q + base, k + base};
    #pragma unroll
    for (int pk = 0; pk < 2; ++pk) {
        __hip_bfloat16* p = ptrs[pk];
        __syncthreads();
        for (int i = t; i < 64 * NDH; i += 256) tile[i / NDH][i % NDH] = __bfloat162float(p[i]);
        __syncthreads();
        #pragma unroll
        for (int e = 0; e < 24; ++e) {
            int i = t + e * 256;
            int sl = i / NDH, dd = i % NDH;
            int axis = dd >> 5, r = dd & 31, j = r & 15;
            float x1 = tile[sl][(axis << 5) + j];
            float x2 = tile[sl][(axis << 5) + 16 + j];
            float cv = cst[sl][(axis << 4) + j], sv = snt[sl][(axis << 4) + j];
            p[i] = __float2bfloat16((r < 16) ? (x1 * cv - x2 * sv) : (x1 * sv + x2 * cv));
        }
    }
}

// ---------------- MFMA bf16 causal flash attention ----------------
// 1024 blocks LPT: bh = bid&31, q-tile = 31-(bid>>5). 64 q-rows/block, 4 waves x 16.
// V pre-transposed globally [bh][d][s] -> staging is 3x b128 like K (no scalar scatter).
// Scaled-domain base-2 online softmax (exp2, scale folded). LDS XOR-swizzled both sides.
// LDS declared short: bit copies only (short->bf16 assignment converts - r6 bug).
__global__ __launch_bounds__(256) void attn_mfma(const __hip_bfloat16* __restrict__ q,
                                                 const __hip_bfloat16* __restrict__ k,
                                                 const __hip_bfloat16* __restrict__ v,
                                                 __hip_bfloat16* __restrict__ out) {
    const float C2 = 0.1020620726159658f * 1.44269504089f;  // (1/sqrt(96))*log2(e)
    __shared__ short Ks[64][128];              // 256B rows (192B used), swizzled
    __shared__ short Vt[96][64];               // [d][kv], 128B rows, swizzled
    __shared__ short Ps[4][16][64];            // per-wave P, 128B rows, swizzled
    int bid = blockIdx.x;
    int bh = bid & 31;
    int tq = 31 - (bid >> 5);                  // LPT: longest blocks dispatch first
    int q0 = tq << 6;
    int t = threadIdx.x, w = t >> 6, l = t & 63;
    int lr = l & 15, lg = l >> 4;
    int qw = q0 + (w << 4);                    // wave's 16 q-rows
    const __hip_bfloat16* qg = q + (size_t)bh * NS * NDH;
    const __hip_bfloat16* kg = k + (size_t)bh * NS * NDH;
    const __hip_bfloat16* vg = v + (size_t)bh * NDH * NS;   // transposed [d][s]
    int b_ = bh >> 3, hh = bh & 7;

    bf16x8 qa[3];
    #pragma unroll
    for (int ks = 0; ks < 3; ++ks)
        qa[ks] = *(const bf16x8*)&qg[(size_t)(qw + lr) * NDH + ks*32 + lg*8];

    f32x4 acco[6];
    #pragma unroll
    for (int dt = 0; dt < 6; ++dt) acco[dt] = (f32x4){0.f, 0.f, 0.f, 0.f};
    float mrow[4], lsum[4];
    #pragma unroll
    for (int r = 0; r < 4; ++r) { mrow[r] = -INFINITY; lsum[r] = 0.f; }

    // staging coords: K 64rows x 12 pieces; V 96rows x 8 pieces (both 16B)
    int krow[3], kslot[3], vrow[3], vslot[3];
    #pragma unroll
    for (int i = 0; i < 3; ++i) {
        int cc = t + i * 256;
        krow[i] = cc / 12; kslot[i] = cc % 12;
        vrow[i] = cc >> 3; vslot[i] = cc & 7;
    }
    int rdsw = (lr & 7) << 3;                  // read-side swizzle (short idx)

    bf16x8 kreg[3], vreg[3];
    #pragma unroll
    for (int i = 0; i < 3; ++i) {
        kreg[i] = *(const bf16x8*)&kg[(size_t)krow[i] * NDH + kslot[i]*8];
        vreg[i] = *(const bf16x8*)&vg[(size_t)vrow[i] * NS + vslot[i]*8];
    }

    for (int c = 0; c <= tq; ++c) {
        int kv0 = c << 6;
        __syncthreads();                       // prior compute done with LDS
        #pragma unroll
        for (int i = 0; i < 3; ++i) {
            *(bf16x8*)&Ks[krow[i]][(kslot[i]*8) ^ ((krow[i] & 7) << 3)] = kreg[i];
            *(bf16x8*)&Vt[vrow[i]][(vslot[i]*8) ^ ((vrow[i] & 7) << 3)] = vreg[i];
        }
        __syncthreads();
        if (c < tq) {                          // prefetch next chunk under compute
            int kv1 = (c + 1) << 6;
            #pragma unroll
            for (int i = 0; i < 3; ++i) {
                kreg[i] = *(const bf16x8*)&kg[(size_t)(kv1 + krow[i]) * NDH + kslot[i]*8];
                vreg[i] = *(const bf16x8*)&vg[(size_t)vrow[i] * NS + kv1 + vslot[i]*8];
            }
        }
        // QK^T: S[16q][64kv]
        f32x4 s[4];
        #pragma unroll
        for (int nt = 0; nt < 4; ++nt) s[nt] = (f32x4){0.f, 0.f, 0.f, 0.f};
        #pragma unroll
        for (int ks = 0; ks < 3; ++ks) {
            #pragma unroll
            for (int nt = 0; nt < 4; ++nt) {
                bf16x8 kb_ = *(const bf16x8*)&Ks[nt*16 + lr][(ks*32 + lg*8) ^ rdsw];
                s[nt] = __builtin_amdgcn_mfma_f32_16x16x32_bf16(qa[ks], kb_, s[nt], 0, 0, 0);
            }
        }
        // mask only the diagonal chunk (raw domain; exp2 of -inf -> 0)
        if (c == tq) {
            #pragma unroll
            for (int r = 0; r < 4; ++r) {
                int qrow = qw + lg*4 + r;
                #pragma unroll
                for (int nt = 0; nt < 4; ++nt) {
                    int col = kv0 + nt*16 + lr;
                    if (col > qrow) s[nt][r] = -INFINITY;
                }
            }
        }
        // scaled-domain online softmax: m,l tracked in C2-units; p = 2^(s*C2 - m2)
        float al[4];
        #pragma unroll
        for (int r = 0; r < 4; ++r) {
            float mx = fmaxf(fmaxf(s[0][r], s[1][r]), fmaxf(s[2][r], s[3][r]));
            #pragma unroll
            for (int o = 1; o < 16; o <<= 1) mx = fmaxf(mx, __shfl_xor(mx, o));
            float m2 = fmaxf(mrow[r], mx * C2);
            al[r] = exp2f(mrow[r] - m2);       // first chunk: 2^-inf = 0
            mrow[r] = m2;
            float rs = 0.f;
            #pragma unroll
            for (int nt = 0; nt < 4; ++nt) {
                float p = exp2f(fmaf(s[nt][r], C2, -m2));
                s[nt][r] = p;
                rs += p;
            }
            #pragma unroll
            for (int o = 1; o < 16; o <<= 1) rs += __shfl_xor(rs, o);
            lsum[r] = lsum[r] * al[r] + rs;
            int prow = lg*4 + r;
            #pragma unroll
            for (int nt = 0; nt < 4; ++nt) {
                __hip_bfloat16 pb = __float2bfloat16(s[nt][r]);
                Ps[w][prow][(nt*16 + lr) ^ ((prow & 7) << 3)] = *(const short*)&pb;
            }
        }
        #pragma unroll
        for (int dt = 0; dt < 6; ++dt)
            #pragma unroll
            for (int r = 0; r < 4; ++r)
                acco[dt][r] *= al[r];
        // PV: O[16q][96d] += P[16x64] x V[64x96]
        #pragma unroll
        for (int ks = 0; ks < 2; ++ks) {
            bf16x8 pa = *(const bf16x8*)&Ps[w][lr][(ks*32 + lg*8) ^ rdsw];
            #pragma unroll
            for (int dt = 0; dt < 6; ++dt) {
                bf16x8 vb_ = *(const bf16x8*)&Vt[dt*16 + lr][(ks*32 + lg*8) ^ rdsw];
                acco[dt] = __builtin_amdgcn_mfma_f32_16x16x32_bf16(pa, vb_, acco[dt], 0, 0, 0);
            }
        }
    }
    // epilogue: divide by l, write bf16 to [B][S][768]
    float inv[4];
    #pragma unroll
    for (int r = 0; r < 4; ++r) inv[r] = 1.0f / lsum[r];
    #pragma unroll
    for (int dt = 0; dt < 6; ++dt)
        #pragma unroll
        for (int r = 0; r < 4; ++r) {
            int row = qw + lg*4 + r;
            out[((size_t)(b_ * NS + row)) * ND + hh * NDH + dt*16 + lr] =
                __float2bfloat16(acco[dt][r] * inv[r]);
        }
}

extern "C" void kernel_launch(void* const* d_in, const int* in_sizes, int n_in,
                              void* d_out, int out_size, void* d_ws, size_t ws_size,
                              hipStream_t stream) {
    const float* src    = (const float*)d_in[0];
    const float* coords = (const float*)d_in[1];
    const float* n1g  = (const float*)d_in[3];
    const float* n1b  = (const float*)d_in[4];
    const float* qkvw = (const float*)d_in[5];
    const float* qkvb = (const float*)d_in[6];
    const float* projw= (const float*)d_in[7];
    const float* projb= (const float*)d_in[8];
    const float* n2g  = (const float*)d_in[9];
    const float* n2b  = (const float*)d_in[10];
    const float* fc1w = (const float*)d_in[11];
    const float* fc1b = (const float*)d_in[12];
    const float* fc2w = (const float*)d_in[13];
    const float* fc2b = (const float*)d_in[14];
    float* out = (float*)d_out;
    float* ws  = (float*)d_ws;

    const size_t N1 = (size_t)NROWS * ND;          // 6291456
    float* x = ws;                                  // [N1] f32 residual stream
    size_t o = N1;
    __hip_bfloat16* qkvwT = (__hip_bfloat16*)(ws + o); o += (768u*2304u)/2;
    __hip_bfloat16* projwT= (__hip_bfloat16*)(ws + o); o += (768u*768u)/2;
    __hip_bfloat16* fc1wT = (__hip_bfloat16*)(ws + o); o += (768u*3072u)/2;
    __hip_bfloat16* fc2wT = (__hip_bfloat16*)(ws + o); o += (3072u*768u)/2;
    __hip_bfloat16* xnb = (__hip_bfloat16*)(ws + o);   // N1 bf16 (LN1 out; later LN2 out)
    size_t o2 = o + N1 / 2;
    __hip_bfloat16* qbf = (__hip_bfloat16*)(ws + o2);
    __hip_bfloat16* kbf = (__hip_bfloat16*)(ws + o2 + N1 / 2);
    __hip_bfloat16* vbf = (__hip_bfloat16*)(ws + o2 + N1);   // TRANSPOSED [bh][dh][s]
    __hip_bfloat16* ao  = (__hip_bfloat16*)(ws + o2 + 3 * N1 / 2);
    __hip_bfloat16* hbuf = qbf;                        // 4*N1 bf16, aliases q/k/v/ao

    // 0) weight transpose+convert
    wtrans_kernel<<<dim3((768/32)*(2304/32)), 256, 0, stream>>>(qkvw, qkvwT, 768, 2304);
    wtrans_kernel<<<dim3((768/32)*(768/32)),  256, 0, stream>>>(projw, projwT, 768, 768);
    wtrans_kernel<<<dim3((768/32)*(3072/32)), 256, 0, stream>>>(fc1w, fc1wT, 768, 3072);
    wtrans_kernel<<<dim3((3072/32)*(768/32)), 256, 0, stream>>>(fc2w, fc2wT, 3072, 768);
    // 1) LN1 -> bf16
    ln_bf16_kernel<<<NROWS, 256, 0, stream>>>(src, n1g, n1b, xnb);
    // 2) QKV GEMM + bias, scatter bf16 q/k [bh][s][dh], v [bh][dh][s]
    gemm_mfma<0><<<dim3(2304/128, NROWS/128), 256, 0, stream>>>(
        xnb, qkvwT, qkvb, NROWS, 2304, ND, nullptr, nullptr, nullptr, qbf, kbf, vbf);
    // 3) RoPE in place on q,k
    rope_bf16_kernel<<<NB * NH * (NS / 64), 256, 0, stream>>>(coords, qbf, kbf);
    // 4) MFMA flash attention -> ao bf16 [B,S,768]
    attn_mfma<<<1024, 256, 0, stream>>>(qbf, kbf, vbf, ao);
    // 5) proj GEMM + bias + residual(src) -> x f32
    gemm_mfma<1><<<dim3(ND/128, NROWS/128), 256, 0, stream>>>(
        ao, projwT, projb, NROWS, ND, ND, x, src, nullptr, nullptr, nullptr, nullptr);
    // 6) LN2 -> bf16
    ln_bf16_kernel<<<NROWS, 256, 0, stream>>>(x, n2g, n2b, xnb);
    // 7) FC1 GEMM + bias + exact GELU -> bf16
    gemm_mfma<2><<<dim3(NHID/128, NROWS/128), 256, 0, stream>>>(
        xnb, fc1wT, fc1b, NROWS, NHID, ND, nullptr, nullptr, hbuf, nullptr, nullptr, nullptr);
    // 8) FC2 GEMM + bias + residual(x) -> out f32
    gemm_mfma<1><<<dim3(ND/128, NROWS/128), 256, 0, stream>>>(
        hbuf, fc2wT, fc2b, NROWS, ND, NHID, out, x, nullptr, nullptr, nullptr, nullptr);
}

// Round 11
// 462.943 us; speedup vs baseline: 1.0453x; 1.0453x over previous
//
#include <hip/hip_runtime.h>
#include <hip/hip_bf16.h>
#include <math.h>

#define NB 4
#define NS 2048
#define ND 768
#define NH 8
#define NDH 96
#define NHID 3072
#define NROWS (NB*NS)

typedef __attribute__((ext_vector_type(8))) short bf16x8;
typedef __attribute__((ext_vector_type(4))) float f32x4;

// async global->LDS, 16B per lane. LDS dest must be wave-uniform base (HW adds lane*16).
#define GLOAD16(gp, lp)                                                          \
    __builtin_amdgcn_global_load_lds(                                            \
        (__attribute__((address_space(1))) void*)(unsigned long long)(gp),       \
        (__attribute__((address_space(3))) void*)(unsigned long long)(lp), 16, 0, 0)

// ---------------- block-wide sum over 256 threads ----------------
static __device__ __forceinline__ float block_sum256(float v) {
    __shared__ float red[4];
    #pragma unroll
    for (int o = 32; o > 0; o >>= 1) v += __shfl_down(v, o);
    int w = threadIdx.x >> 6;
    __syncthreads();
    if ((threadIdx.x & 63) == 0) red[w] = v;
    __syncthreads();
    return red[0] + red[1] + red[2] + red[3];
}

// ---------------- LayerNorm: f32 in -> bf16 out ----------------
__global__ __launch_bounds__(256) void ln_bf16_kernel(const float* __restrict__ in,
                                                      const float* __restrict__ g,
                                                      const float* __restrict__ bta,
                                                      __hip_bfloat16* __restrict__ out) {
    int row = blockIdx.x;
    const float* x = in + (size_t)row * ND;
    int t = threadIdx.x;
    float v0 = x[t], v1 = x[t + 256], v2 = x[t + 512];
    float mu = block_sum256(v0 + v1 + v2) * (1.0f / ND);
    float d0 = v0 - mu, d1 = v1 - mu, d2 = v2 - mu;
    float var = block_sum256(d0*d0 + d1*d1 + d2*d2) * (1.0f / ND);
    float rs = rsqrtf(var + 1e-6f);
    __hip_bfloat16* o = out + (size_t)row * ND;
    o[t]       = __float2bfloat16(d0 * rs * g[t]       + bta[t]);
    o[t + 256] = __float2bfloat16(d1 * rs * g[t + 256] + bta[t + 256]);
    o[t + 512] = __float2bfloat16(d2 * rs * g[t + 512] + bta[t + 512]);
}

// ---------------- weight transpose+convert: w[K][N] f32 -> wT[N][K] bf16 ----------------
__global__ __launch_bounds__(256) void wtrans_kernel(const float* __restrict__ w,
                                                     __hip_bfloat16* __restrict__ wT,
                                                     int K, int N) {
    __shared__ float tile[32][33];
    int nb = N >> 5;
    int k0 = (blockIdx.x / nb) << 5, n0 = (blockIdx.x % nb) << 5;
    int t = threadIdx.x;
    int rr = t >> 5, cc = t & 31;
    #pragma unroll
    for (int j = 0; j < 4; ++j)
        tile[rr + j*8][cc] = w[(size_t)(k0 + rr + j*8) * N + n0 + cc];
    __syncthreads();
    #pragma unroll
    for (int j = 0; j < 4; ++j)
        wT[(size_t)(n0 + rr + j*8) * K + k0 + cc] = __float2bfloat16(tile[cc][rr + j*8]);
}

// ---------------- bf16 MFMA GEMM: C[M][N] = A[M][K] * BT[N][K]^T ----------------
// 128x128 tile, BK=64, 256 thr (4 waves 2x2), global_load_lds w/ XOR-swizzled source.
// XCD-chunked blockIdx remap (T1, bijective: all grids %8==0).
// EPI: 0 = +bias, scatter bf16 q/k/v row-major [bh][s][dh] (V transposed later in rope);
//      1 = +bias+res -> f32; 2 = +bias+GELU -> bf16
template<int EPI>
__global__ __launch_bounds__(256) void gemm_mfma(
        const __hip_bfloat16* __restrict__ A, const __hip_bfloat16* __restrict__ BT,
        const float* __restrict__ bias, int M, int N, int K,
        float* __restrict__ Cf, const float* __restrict__ res,
        __hip_bfloat16* __restrict__ Cb,
        __hip_bfloat16* __restrict__ qo, __hip_bfloat16* __restrict__ ko,
        __hip_bfloat16* __restrict__ vo) {
    __shared__ __attribute__((aligned(16))) __hip_bfloat16 As[128][64];
    __shared__ __attribute__((aligned(16))) __hip_bfloat16 Bs[128][64];
    // XCD-aware remap: each XCD gets a contiguous chunk of x-major block order
    int gxd = gridDim.x;
    int lin = blockIdx.y * gxd + blockIdx.x;
    int cpx = (gxd * gridDim.y) >> 3;
    int lin2 = (lin & 7) * cpx + (lin >> 3);
    int bx = lin2 % gxd, by = lin2 / gxd;
    int t = threadIdx.x, w = t >> 6, l = t & 63;
    int lr = l & 15, lg = l >> 4;
    int wr = w >> 1, wc = w & 1;

    int off  = w * 1024 + l * 16;
    int srow = off >> 7;
    int scol = off & 127;
    int scolS = scol ^ ((srow & 7) << 4);
    const char* ap = (const char*)(A  + (size_t)(by * 128 + srow) * K) + scolS;
    const char* bp = (const char*)(BT + (size_t)(bx * 128 + srow) * K) + scolS;
    size_t rstep = (size_t)32 * K * 2;
    char* asl = ((char*)As) + w * 1024;
    char* bsl = ((char*)Bs) + w * 1024;

    f32x4 acc[4][4];
    #pragma unroll
    for (int i = 0; i < 4; ++i)
        #pragma unroll
        for (int j = 0; j < 4; ++j) acc[i][j] = (f32x4){0.f, 0.f, 0.f, 0.f};

    int mask = (lr & 7) << 4;
    const char* asb = (const char*)As;
    const char* bsb = (const char*)Bs;

    for (int k0 = 0; k0 < K; k0 += 64) {
        __syncthreads();
        #pragma unroll
        for (int i = 0; i < 4; ++i) {
            GLOAD16(ap + i * rstep, asl + i * 4096);
            GLOAD16(bp + i * rstep, bsl + i * 4096);
        }
        ap += 128; bp += 128;
        __syncthreads();
        #pragma unroll
        for (int ks = 0; ks < 2; ++ks) {
            bf16x8 a[4], b[4];
            #pragma unroll
            for (int x = 0; x < 4; ++x) {
                int ra = (wr << 6) + x*16 + lr;
                int rb = (wc << 6) + x*16 + lr;
                int cb = ((ks * 64 + lg * 16) ^ mask);
                a[x] = *(const bf16x8*)(asb + ra * 128 + cb);
                b[x] = *(const bf16x8*)(bsb + rb * 128 + cb);
            }
            #pragma unroll
            for (int mt = 0; mt < 4; ++mt)
                #pragma unroll
                for (int nt = 0; nt < 4; ++nt)
                    acc[mt][nt] = __builtin_amdgcn_mfma_f32_16x16x32_bf16(a[mt], b[nt], acc[mt][nt], 0, 0, 0);
        }
    }

    int rbase = by * 128 + (wr << 6) + lg * 4;
    int cbase = bx * 128 + (wc << 6) + lr;
    #pragma unroll
    for (int nt = 0; nt < 4; ++nt) {
        int gc = cbase + nt * 16;
        float bv = bias[gc];
        #pragma unroll
        for (int mt = 0; mt < 4; ++mt) {
            #pragma unroll
            for (int rr = 0; rr < 4; ++rr) {
                int gr = rbase + mt * 16 + rr;
                float val = acc[mt][nt][rr] + bv;
                if (EPI == 0) {
                    int which = gc / ND;
                    int ccc = gc - which * ND;
                    int hh = ccc / NDH, dd = ccc - hh * NDH;
                    int b_ = gr >> 11, s_ = gr & (NS - 1);
                    __hip_bfloat16* dst = (which == 0) ? qo : (which == 1) ? ko : vo;
                    dst[(size_t)((b_ * NH + hh) * NS + s_) * NDH + dd] = __float2bfloat16(val);
                } else if (EPI == 1) {
                    Cf[(size_t)gr * N + gc] = res[(size_t)gr * N + gc] + val;
                } else {
                    Cb[(size_t)gr * N + gc] =
                        __float2bfloat16(0.5f * val * (1.0f + erff(val * 0.70710678118f)));
                }
            }
        }
    }
}

// ---------------- 3D RoPE: rotate q,k bf16 in place; transpose v -> [bh][d][s] ----------------
__global__ __launch_bounds__(256) void rope_bf16_kernel(const float* __restrict__ coords,
                                                        __hip_bfloat16* __restrict__ q,
                                                        __hip_bfloat16* __restrict__ k,
                                                        const __hip_bfloat16* __restrict__ vin,
                                                        __hip_bfloat16* __restrict__ vT) {
    __shared__ float tile[64][97];   // 97-pad: conflict-free column reads in transpose
    __shared__ float cst[64][49];
    __shared__ float snt[64][49];
    int nblk = NS / 64;
    int bh = blockIdx.x / nblk;
    int s0 = (blockIdx.x % nblk) * 64;
    int b_ = bh / NH;
    int t = threadIdx.x;
    for (int i = t; i < 64 * 48; i += 256) {
        int sl = i / 48, f = i - sl * 48;
        int axis = f >> 4, j = f & 15;
        float c = coords[(size_t)(b_ * NS + s0 + sl) * 3 + axis];
        float ang = c * powf(10000.0f, -(float)j * (1.0f / 16.0f));
        float sv, cv;
        sincosf(ang, &sv, &cv);
        cst[sl][f] = cv; snt[sl][f] = sv;
    }
    size_t base = (size_t)(bh * NS + s0) * NDH;
    __hip_bfloat16* ptrs[2] = {q + base, k + base};
    #pragma unroll
    for (int pk = 0; pk < 2; ++pk) {
        __hip_bfloat16* p = ptrs[pk];
        __syncthreads();
        for (int i = t; i < 64 * NDH; i += 256) tile[i / NDH][i % NDH] = __bfloat162float(p[i]);
        __syncthreads();
        #pragma unroll
        for (int e = 0; e < 24; ++e) {
            int i = t + e * 256;
            int sl = i / NDH, dd = i % NDH;
            int axis = dd >> 5, r = dd & 31, j = r & 15;
            float x1 = tile[sl][(axis << 5) + j];
            float x2 = tile[sl][(axis << 5) + 16 + j];
            float cv = cst[sl][(axis << 4) + j], sv = snt[sl][(axis << 4) + j];
            p[i] = __float2bfloat16((r < 16) ? (x1 * cv - x2 * sv) : (x1 * sv + x2 * cv));
        }
    }
    // ---- V transpose: [s][d] -> [d][s] (both sides coalesced; LDS conflict-free) ----
    __syncthreads();
    const __hip_bfloat16* vp = vin + base;
    for (int i = t; i < 64 * NDH; i += 256) tile[i / NDH][i % NDH] = __bfloat162float(vp[i]);
    __syncthreads();
    __hip_bfloat16* vtp = vT + (size_t)bh * NDH * NS;
    #pragma unroll
    for (int e = 0; e < 24; ++e) {
        int i = t + e * 256;
        int dd = i >> 6, sl = i & 63;
        vtp[(size_t)dd * NS + s0 + sl] = __float2bfloat16(tile[sl][dd]);
    }
}

// ---------------- MFMA bf16 causal flash attention ----------------
// 1024 blocks LPT: bh = bid&31, q-tile = 31-(bid>>5). 64 q-rows/block, 4 waves x 16.
// V pre-transposed globally [bh][d][s] -> staging is 3x b128 like K.
// Scaled-domain base-2 online softmax + T13-lite rescale skip. LDS XOR-swizzled.
// LDS declared short: bit copies only (short->bf16 assignment converts - r6 bug).
__global__ __launch_bounds__(256) void attn_mfma(const __hip_bfloat16* __restrict__ q,
                                                 const __hip_bfloat16* __restrict__ k,
                                                 const __hip_bfloat16* __restrict__ v,
                                                 __hip_bfloat16* __restrict__ out) {
    const float C2 = 0.1020620726159658f * 1.44269504089f;  // (1/sqrt(96))*log2(e)
    __shared__ short Ks[64][128];              // 256B rows (192B used), swizzled
    __shared__ short Vt[96][64];               // [d][kv], 128B rows, swizzled
    __shared__ short Ps[4][16][64];            // per-wave P, 128B rows, swizzled
    int bid = blockIdx.x;
    int bh = bid & 31;
    int tq = 31 - (bid >> 5);                  // LPT: longest blocks dispatch first
    int q0 = tq << 6;
    int t = threadIdx.x, w = t >> 6, l = t & 63;
    int lr = l & 15, lg = l >> 4;
    int qw = q0 + (w << 4);                    // wave's 16 q-rows
    const __hip_bfloat16* qg = q + (size_t)bh * NS * NDH;
    const __hip_bfloat16* kg = k + (size_t)bh * NS * NDH;
    const __hip_bfloat16* vg = v + (size_t)bh * NDH * NS;   // transposed [d][s]
    int b_ = bh >> 3, hh = bh & 7;

    bf16x8 qa[3];
    #pragma unroll
    for (int ks = 0; ks < 3; ++ks)
        qa[ks] = *(const bf16x8*)&qg[(size_t)(qw + lr) * NDH + ks*32 + lg*8];

    f32x4 acco[6];
    #pragma unroll
    for (int dt = 0; dt < 6; ++dt) acco[dt] = (f32x4){0.f, 0.f, 0.f, 0.f};
    float mrow[4], lsum[4];
    #pragma unroll
    for (int r = 0; r < 4; ++r) { mrow[r] = -INFINITY; lsum[r] = 0.f; }

    // staging coords: K 64rows x 12 pieces; V 96rows x 8 pieces (both 16B)
    int krow[3], kslot[3], vrow[3], vslot[3];
    #pragma unroll
    for (int i = 0; i < 3; ++i) {
        int cc = t + i * 256;
        krow[i] = cc / 12; kslot[i] = cc % 12;
        vrow[i] = cc >> 3; vslot[i] = cc & 7;
    }
    int rdsw = (lr & 7) << 3;                  // read-side swizzle (short idx)

    bf16x8 kreg[3], vreg[3];
    #pragma unroll
    for (int i = 0; i < 3; ++i) {
        kreg[i] = *(const bf16x8*)&kg[(size_t)krow[i] * NDH + kslot[i]*8];
        vreg[i] = *(const bf16x8*)&vg[(size_t)vrow[i] * NS + vslot[i]*8];
    }

    for (int c = 0; c <= tq; ++c) {
        int kv0 = c << 6;
        __syncthreads();                       // prior compute done with LDS
        #pragma unroll
        for (int i = 0; i < 3; ++i) {
            *(bf16x8*)&Ks[krow[i]][(kslot[i]*8) ^ ((krow[i] & 7) << 3)] = kreg[i];
            *(bf16x8*)&Vt[vrow[i]][(vslot[i]*8) ^ ((vrow[i] & 7) << 3)] = vreg[i];
        }
        __syncthreads();
        if (c < tq) {                          // prefetch next chunk under compute
            int kv1 = (c + 1) << 6;
            #pragma unroll
            for (int i = 0; i < 3; ++i) {
                kreg[i] = *(const bf16x8*)&kg[(size_t)(kv1 + krow[i]) * NDH + kslot[i]*8];
                vreg[i] = *(const bf16x8*)&vg[(size_t)vrow[i] * NS + kv1 + vslot[i]*8];
            }
        }
        // QK^T: S[16q][64kv]
        f32x4 s[4];
        #pragma unroll
        for (int nt = 0; nt < 4; ++nt) s[nt] = (f32x4){0.f, 0.f, 0.f, 0.f};
        #pragma unroll
        for (int ks = 0; ks < 3; ++ks) {
            #pragma unroll
            for (int nt = 0; nt < 4; ++nt) {
                bf16x8 kb_ = *(const bf16x8*)&Ks[nt*16 + lr][(ks*32 + lg*8) ^ rdsw];
                s[nt] = __builtin_amdgcn_mfma_f32_16x16x32_bf16(qa[ks], kb_, s[nt], 0, 0, 0);
            }
        }
        // mask only the diagonal chunk (raw domain; exp2 of -inf -> 0)
        if (c == tq) {
            #pragma unroll
            for (int r = 0; r < 4; ++r) {
                int qrow = qw + lg*4 + r;
                #pragma unroll
                for (int nt = 0; nt < 4; ++nt) {
                    int col = kv0 + nt*16 + lr;
                    if (col > qrow) s[nt][r] = -INFINITY;
                }
            }
        }
        // scaled-domain online softmax: m,l tracked in C2-units; p = 2^(s*C2 - m2)
        float al[4];
        #pragma unroll
        for (int r = 0; r < 4; ++r) {
            float mx = fmaxf(fmaxf(s[0][r], s[1][r]), fmaxf(s[2][r], s[3][r]));
            #pragma unroll
            for (int o = 1; o < 16; o <<= 1) mx = fmaxf(mx, __shfl_xor(mx, o));
            float m2 = fmaxf(mrow[r], mx * C2);
            al[r] = exp2f(mrow[r] - m2);       // ==1.0 exactly when max unchanged
            mrow[r] = m2;
            float rs = 0.f;
            #pragma unroll
            for (int nt = 0; nt < 4; ++nt) {
                float p = exp2f(fmaf(s[nt][r], C2, -m2));
                s[nt][r] = p;
                rs += p;
            }
            #pragma unroll
            for (int o = 1; o < 16; o <<= 1) rs += __shfl_xor(rs, o);
            lsum[r] = lsum[r] * al[r] + rs;
            int prow = lg*4 + r;
            #pragma unroll
            for (int nt = 0; nt < 4; ++nt) {
                __hip_bfloat16 pb = __float2bfloat16(s[nt][r]);
                Ps[w][prow][(nt*16 + lr) ^ ((prow & 7) << 3)] = *(const short*)&pb;
            }
        }
        // T13-lite: skip the 24-mult O-rescale when no row's max grew (al==1 all)
        if (__any((al[0] != 1.f) | (al[1] != 1.f) | (al[2] != 1.f) | (al[3] != 1.f))) {
            #pragma unroll
            for (int dt = 0; dt < 6; ++dt)
                #pragma unroll
                for (int r = 0; r < 4; ++r)
                    acco[dt][r] *= al[r];
        }
        // PV: O[16q][96d] += P[16x64] x V[64x96]
        #pragma unroll
        for (int ks = 0; ks < 2; ++ks) {
            bf16x8 pa = *(const bf16x8*)&Ps[w][lr][(ks*32 + lg*8) ^ rdsw];
            #pragma unroll
            for (int dt = 0; dt < 6; ++dt) {
                bf16x8 vb_ = *(const bf16x8*)&Vt[dt*16 + lr][(ks*32 + lg*8) ^ rdsw];
                acco[dt] = __builtin_amdgcn_mfma_f32_16x16x32_bf16(pa, vb_, acco[dt], 0, 0, 0);
            }
        }
    }
    // epilogue: divide by l, write bf16 to [B][S][768]
    float inv[4];
    #pragma unroll
    for (int r = 0; r < 4; ++r) inv[r] = 1.0f / lsum[r];
    #pragma unroll
    for (int dt = 0; dt < 6; ++dt)
        #pragma unroll
        for (int r = 0; r < 4; ++r) {
            int row = qw + lg*4 + r;
            out[((size_t)(b_ * NS + row)) * ND + hh * NDH + dt*16 + lr] =
                __float2bfloat16(acco[dt][r] * inv[r]);
        }
}

extern "C" void kernel_launch(void* const* d_in, const int* in_sizes, int n_in,
                              void* d_out, int out_size, void* d_ws, size_t ws_size,
                              hipStream_t stream) {
    const float* src    = (const float*)d_in[0];
    const float* coords = (const float*)d_in[1];
    const float* n1g  = (const float*)d_in[3];
    const float* n1b  = (const float*)d_in[4];
    const float* qkvw = (const float*)d_in[5];
    const float* qkvb = (const float*)d_in[6];
    const float* projw= (const float*)d_in[7];
    const float* projb= (const float*)d_in[8];
    const float* n2g  = (const float*)d_in[9];
    const float* n2b  = (const float*)d_in[10];
    const float* fc1w = (const float*)d_in[11];
    const float* fc1b = (const float*)d_in[12];
    const float* fc2w = (const float*)d_in[13];
    const float* fc2b = (const float*)d_in[14];
    float* out = (float*)d_out;
    float* ws  = (float*)d_ws;

    const size_t N1 = (size_t)NROWS * ND;          // 6291456
    float* x = ws;                                  // [N1] f32 residual stream
    size_t o = N1;
    __hip_bfloat16* qkvwT = (__hip_bfloat16*)(ws + o); o += (768u*2304u)/2;
    __hip_bfloat16* projwT= (__hip_bfloat16*)(ws + o); o += (768u*768u)/2;
    __hip_bfloat16* fc1wT = (__hip_bfloat16*)(ws + o); o += (768u*3072u)/2;
    __hip_bfloat16* fc2wT = (__hip_bfloat16*)(ws + o); o += (3072u*768u)/2;
    __hip_bfloat16* xnb = (__hip_bfloat16*)(ws + o);   // N1 bf16 (LN1 out; later LN2 out)
    size_t o2 = o + N1 / 2;
    __hip_bfloat16* qbf = (__hip_bfloat16*)(ws + o2);
    __hip_bfloat16* kbf = (__hip_bfloat16*)(ws + o2 + N1 / 2);
    __hip_bfloat16* vbf = (__hip_bfloat16*)(ws + o2 + N1);   // TRANSPOSED [bh][dh][s]
    __hip_bfloat16* ao  = (__hip_bfloat16*)(ws + o2 + 3 * N1 / 2);
    __hip_bfloat16* vtmp= (__hip_bfloat16*)(ws + o2 + 2 * N1); // V row-major staging
    __hip_bfloat16* hbuf = qbf;                        // 4*N1 bf16, aliases q/k/v/ao

    // 0) weight transpose+convert
    wtrans_kernel<<<dim3((768/32)*(2304/32)), 256, 0, stream>>>(qkvw, qkvwT, 768, 2304);
    wtrans_kernel<<<dim3((768/32)*(768/32)),  256, 0, stream>>>(projw, projwT, 768, 768);
    wtrans_kernel<<<dim3((768/32)*(3072/32)), 256, 0, stream>>>(fc1w, fc1wT, 768, 3072);
    wtrans_kernel<<<dim3((3072/32)*(768/32)), 256, 0, stream>>>(fc2w, fc2wT, 3072, 768);
    // 1) LN1 -> bf16
    ln_bf16_kernel<<<NROWS, 256, 0, stream>>>(src, n1g, n1b, xnb);
    // 2) QKV GEMM + bias, scatter bf16 q/k/vtmp row-major [bh][s][dh] (coalesced)
    gemm_mfma<0><<<dim3(2304/128, NROWS/128), 256, 0, stream>>>(
        xnb, qkvwT, qkvb, NROWS, 2304, ND, nullptr, nullptr, nullptr, qbf, kbf, vtmp);
    // 3) RoPE in place on q,k + V transpose vtmp -> vbf [bh][dh][s]
    rope_bf16_kernel<<<NB * NH * (NS / 64), 256, 0, stream>>>(coords, qbf, kbf, vtmp, vbf);
    // 4) MFMA flash attention -> ao bf16 [B,S,768]
    attn_mfma<<<1024, 256, 0, stream>>>(qbf, kbf, vbf, ao);
    // 5) proj GEMM + bias + residual(src) -> x f32
    gemm_mfma<1><<<dim3(ND/128, NROWS/128), 256, 0, stream>>>(
        ao, projwT, projb, NROWS, ND, ND, x, src, nullptr, nullptr, nullptr, nullptr);
    // 6) LN2 -> bf16
    ln_bf16_kernel<<<NROWS, 256, 0, stream>>>(x, n2g, n2b, xnb);
    // 7) FC1 GEMM + bias + exact GELU -> bf16
    gemm_mfma<2><<<dim3(NHID/128, NROWS/128), 256, 0, stream>>>(
        xnb, fc1wT, fc1b, NROWS, NHID, ND, nullptr, nullptr, hbuf, nullptr, nullptr, nullptr);
    // 8) FC2 GEMM + bias + residual(x) -> out f32
    gemm_mfma<1><<<dim3(ND/128, NROWS/128), 256, 0, stream>>>(
        hbuf, fc2wT, fc2b, NROWS, ND, NHID, out, x, nullptr, nullptr, nullptr, nullptr);
}